// Round 5
// baseline (4568.169 us; speedup 1.0000x reference)
//
#include <hip/hip_runtime.h>
#include <hip/hip_bf16.h>

typedef __hip_bfloat16 bf16;

static __device__ __forceinline__ float b2f(bf16 x) { return __bfloat162float(x); }
static __device__ __forceinline__ bf16  f2b(float x) { return __float2bfloat16(x); }

// ---- problem constants ----
constexpr int D0 = 240, H0 = 144, W0 = 240;
constexpr int V  = D0 * H0 * W0;          // 8,294,400 voxels
constexpr int NPIX = 480 * 640;           // 307,200 pixels
constexpr int C0 = 12;                    // input feature channels
constexpr int D1 = 120, H1 = 72, W1 = 120;
constexpr int N1 = D1 * H1 * W1;          // 1,036,800
constexpr int D2 = 60, H2 = 36, W2 = 60;
constexpr int N2 = D2 * H2 * W2;          // 129,600

constexpr size_t SEG_BYTES = (size_t)C0 * V * sizeof(bf16);   // 199,065,600
constexpr size_t WIN_BYTES = (size_t)V * sizeof(unsigned);    // 33,177,600 (== V floats)
constexpr int ZCHUNKS = (int)((SEG_BYTES + WIN_BYTES) / 16);  // 14,515,200 uint4
// Workspace peak: SEG_BYTES + 16*N1*4 = 265,420,800 bytes — proven safe (R2 ran it).

// ============================================================
// Zero-fill (uint4)
// ============================================================
__global__ void kz_zero16(uint4* __restrict__ p, int nchunks) {
    int i = blockIdx.x * 256 + threadIdx.x;
    if (i >= nchunks) return;
    p[i] = make_uint4(0u, 0u, 0u, 0u);
}

// ============================================================
// Scatter: last-write-wins via winner = max(pixel_index+1)
// ============================================================
__global__ void kz_scatter_win(const int* __restrict__ depth, unsigned* __restrict__ winner) {
    int p = blockIdx.x * 256 + threadIdx.x;
    if (p >= NPIX) return;
    int d = depth[p];
    if (d > 0 && d < V) atomicMax(&winner[d], (unsigned)(p + 1));
}

__global__ void kz_scatter_write(const int* __restrict__ depth, const unsigned* __restrict__ winner,
                                 const float* __restrict__ feat, bf16* __restrict__ segA) {
    int p = blockIdx.x * 256 + threadIdx.x;
    if (p >= NPIX) return;
    int d = depth[p];
    if (d > 0 && d < V && winner[d] == (unsigned)(p + 1)) {
#pragma unroll
        for (int c = 0; c < C0; ++c)
            segA[(size_t)c * V + d] = f2b(feat[c * NPIX + p]);
    }
}

// ============================================================
// Fill pass A (one channel): 3-tap sums along W (zero padded) -> f32 tmp
// ============================================================
__global__ void kz_sumw(const bf16* __restrict__ seg, float* __restrict__ tmp) {
    int i = blockIdx.x * 256 + threadIdx.x;
    if (i >= V) return;
    int w = i % W0;
    float s = b2f(seg[i]);
    if (w > 0)      s += b2f(seg[i - 1]);
    if (w < W0 - 1) s += b2f(seg[i + 1]);
    tmp[i] = s;
}

// ============================================================
// Fill pass B (one channel, IN-PLACE): 9-tap (d,h) sum of row-sums, /27, select
// ============================================================
__global__ void kz_fill(bf16* __restrict__ raw, const float* __restrict__ tmp) {
    int i = blockIdx.x * 256 + threadIdx.x;
    if (i >= V) return;
    bf16 rv = raw[i];
    if (b2f(rv) != 0.f) return;               // keep raw value
    int w = i % W0;
    int t = i / W0;
    int h = t % H0;
    int d = t / H0;
    float s = 0.f;
#pragma unroll
    for (int dd = -1; dd <= 1; ++dd) {
        int d2 = d + dd;
        if (d2 < 0 || d2 >= D0) continue;
#pragma unroll
        for (int dh = -1; dh <= 1; ++dh) {
            int h2 = h + dh;
            if (h2 < 0 || h2 >= H0) continue;
            s += tmp[(d2 * H0 + h2) * W0 + w];
        }
    }
    raw[i] = f2b(s * (1.0f / 27.0f));
}

// ============================================================
// Downsample 1: conv3d 12->4 (k3,s2,p1, no bias) ++ maxpool2 of 12ch, relu
// input bf16 [12][V], f32 weights, output f32 [16][N1]
// ============================================================
__global__ void kz_ds1(const bf16* __restrict__ seg, const float* __restrict__ w,
                       float* __restrict__ out) {
    __shared__ float wl[4 * 12 * 27];
    for (int t = threadIdx.x; t < 4 * 12 * 27; t += 256) wl[t] = w[t];
    __syncthreads();
    int o = blockIdx.x * 256 + threadIdx.x;
    if (o >= N1) return;
    int wo = o % W1;
    int t  = o / W1;
    int ho = t % H1;
    int d0 = t / H1;
    float acc[4] = {0.f, 0.f, 0.f, 0.f};
    for (int ci = 0; ci < 12; ++ci) {
        const bf16* base = seg + (size_t)ci * V;
        float mx = -1e30f;
        for (int kd = 0; kd < 3; ++kd) {
            int d2 = 2 * d0 - 1 + kd;
            bool dv = (d2 >= 0 && d2 < D0);
            for (int kh = 0; kh < 3; ++kh) {
                int h2 = 2 * ho - 1 + kh;
                bool hv = (h2 >= 0 && h2 < H0);
                for (int kw = 0; kw < 3; ++kw) {
                    int w2 = 2 * wo - 1 + kw;
                    float v = 0.f;
                    if (dv && hv && w2 >= 0 && w2 < W0)
                        v = b2f(base[(d2 * H0 + h2) * W0 + w2]);
                    int wi = ci * 27 + kd * 9 + kh * 3 + kw;
#pragma unroll
                    for (int m = 0; m < 4; ++m) acc[m] += v * wl[m * 324 + wi];
                    if (kd >= 1 && kh >= 1 && kw >= 1) mx = fmaxf(mx, v);  // pool = inner 2x2x2
                }
            }
        }
        out[(4 + ci) * N1 + o] = fmaxf(mx, 0.f);
    }
#pragma unroll
    for (int m = 0; m < 4; ++m) out[m * N1 + o] = fmaxf(acc[m], 0.f);
}

// ============================================================
// Downsample 2: conv3d 16->16 (k3,s2,p1) ++ maxpool2 of 16ch, relu (f32 in/out)
// ============================================================
__global__ void kz_ds2(const float* __restrict__ in, const float* __restrict__ w,
                       float* __restrict__ out) {
    __shared__ float wl[16 * 16 * 27];
    for (int t = threadIdx.x; t < 16 * 16 * 27; t += 256) wl[t] = w[t];
    __syncthreads();
    int o = blockIdx.x * 256 + threadIdx.x;
    if (o >= N2) return;
    int wo = o % W2;
    int t  = o / W2;
    int ho = t % H2;
    int d0 = t / H2;
    float acc[16];
#pragma unroll
    for (int m = 0; m < 16; ++m) acc[m] = 0.f;
    for (int ci = 0; ci < 16; ++ci) {
        const float* base = in + ci * N1;
        float mx = -1e30f;
        for (int kd = 0; kd < 3; ++kd) {
            int d2 = 2 * d0 - 1 + kd;
            bool dv = (d2 >= 0 && d2 < D1);
            for (int kh = 0; kh < 3; ++kh) {
                int h2 = 2 * ho - 1 + kh;
                bool hv = (h2 >= 0 && h2 < H1);
                for (int kw = 0; kw < 3; ++kw) {
                    int w2 = 2 * wo - 1 + kw;
                    float v = 0.f;
                    if (dv && hv && w2 >= 0 && w2 < W1)
                        v = base[(d2 * H1 + h2) * W1 + w2];
                    int wi = ci * 27 + kd * 9 + kh * 3 + kw;
#pragma unroll
                    for (int m = 0; m < 16; ++m) acc[m] += v * wl[m * 432 + wi];
                    if (kd >= 1 && kh >= 1 && kw >= 1) mx = fmaxf(mx, v);
                }
            }
        }
        out[(16 + ci) * N2 + o] = fmaxf(mx, 0.f);
    }
#pragma unroll
    for (int m = 0; m < 16; ++m) out[m * N2 + o] = fmaxf(acc[m], 0.f);
}

// ============================================================
// Pointwise (1x1x1) conv, optional residual, relu, f32 out
// ============================================================
template <int CIN, int COUT, bool HASRES>
__global__ void kz_pw(const float* __restrict__ in, const float* __restrict__ w,
                      const float* __restrict__ res, float* __restrict__ outf, int N) {
    __shared__ float wl[CIN * COUT];
    for (int t = threadIdx.x; t < CIN * COUT; t += 256) wl[t] = w[t];
    __syncthreads();
    int o = blockIdx.x * 256 + threadIdx.x;
    if (o >= N) return;
    float acc[COUT];
#pragma unroll
    for (int m = 0; m < COUT; ++m) acc[m] = 0.f;
    for (int ci = 0; ci < CIN; ++ci) {
        float v = in[ci * N + o];
#pragma unroll
        for (int m = 0; m < COUT; ++m) acc[m] += v * wl[m * CIN + ci];
    }
#pragma unroll
    for (int m = 0; m < COUT; ++m) {
        float r = acc[m];
        if (HASRES) r += res[m * N + o];
        outf[m * N + o] = fmaxf(r, 0.f);
    }
}

// ============================================================
// Bottleneck middle conv: C->C, kernel (KD,KH,KW) same-pad on >1 dims,
// + bias + up to 2 residual adds + relu. f32 in/out.
// ============================================================
template <int C, int KD, int KH, int KW, int NADD>
__global__ void kz_bconv(const float* __restrict__ in, const float* __restrict__ w,
                         const float* __restrict__ b,
                         const float* __restrict__ add1, const float* __restrict__ add2,
                         float* __restrict__ out, int Dd, int Hh, int Ww, int N) {
    __shared__ float wl[C * C * KD * KH * KW];
    __shared__ float bl[C];
    for (int t = threadIdx.x; t < C * C * KD * KH * KW; t += 256) wl[t] = w[t];
    if (threadIdx.x < C) bl[threadIdx.x] = b[threadIdx.x];
    __syncthreads();
    int o = blockIdx.x * 256 + threadIdx.x;
    if (o >= N) return;
    int wo = o % Ww;
    int t  = o / Ww;
    int ho = t % Hh;
    int d0 = t / Hh;
    float acc[C];
#pragma unroll
    for (int m = 0; m < C; ++m) acc[m] = bl[m];
    for (int ci = 0; ci < C; ++ci) {
        const float* base = in + ci * N;
#pragma unroll
        for (int kd = 0; kd < KD; ++kd) {
            int d2 = d0 + kd - KD / 2;
            if (d2 < 0 || d2 >= Dd) continue;
#pragma unroll
            for (int kh = 0; kh < KH; ++kh) {
                int h2 = ho + kh - KH / 2;
                if (h2 < 0 || h2 >= Hh) continue;
#pragma unroll
                for (int kw = 0; kw < KW; ++kw) {
                    int w2 = wo + kw - KW / 2;
                    if (w2 < 0 || w2 >= Ww) continue;
                    float v = base[(d2 * Hh + h2) * Ww + w2];
#pragma unroll
                    for (int m = 0; m < C; ++m)
                        acc[m] += v * wl[((m * C + ci) * KD + kd) * (KH * KW) + kh * KW + kw];
                }
            }
        }
    }
#pragma unroll
    for (int m = 0; m < C; ++m) {
        float r = acc[m];
        if (NADD >= 1) r += add1[m * N + o];
        if (NADD >= 2) r += add2[m * N + o];
        out[m * N + o] = fmaxf(r, 0.f);
    }
}

// ============================================================
extern "C" void kernel_launch(void* const* d_in, const int* in_sizes, int n_in,
                              void* d_out, int out_size, void* d_ws, size_t ws_size,
                              hipStream_t stream) {
    const float* feat   = (const float*)d_in[0];
    const int*   depth  = (const int*)d_in[1];
    const float* w_ds1  = (const float*)d_in[2];
    const float* b1_win = (const float*)d_in[3];
    const float* b1w133 = (const float*)d_in[4];
    const float* b1b133 = (const float*)d_in[5];
    const float* b1w331 = (const float*)d_in[6];
    const float* b1b331 = (const float*)d_in[7];
    const float* b1w313 = (const float*)d_in[8];
    const float* b1b313 = (const float*)d_in[9];
    const float* b1wout = (const float*)d_in[10];
    const float* w_ds2  = (const float*)d_in[11];
    const float* b2_win = (const float*)d_in[12];
    const float* b2w133 = (const float*)d_in[13];
    const float* b2b133 = (const float*)d_in[14];
    const float* b2w331 = (const float*)d_in[15];
    const float* b2b331 = (const float*)d_in[16];
    const float* b2w313 = (const float*)d_in[17];
    const float* b2b313 = (const float*)d_in[18];
    const float* b2wout = (const float*)d_in[19];

    char* base = (char*)d_ws;

    // --- Region layout (time-shared; peak = SEG_BYTES + 66.4MB = 265.4 MB) ---
    bf16* segA = (bf16*)base;                             // [0, SEG) raw volume, filled in-place
    unsigned* winner = (unsigned*)(base + SEG_BYTES);     // [SEG, SEG+33.2MB)
    float*    tmp    = (float*)(base + SEG_BYTES);        // same region (f32[V] == 33.2MB), after winner dies
    float*    x1     = (float*)(base + SEG_BYTES);        // same region, after tmp dies (16*N1 f32 = 66.4MB)
    float* y0  = (float*)base;                            // after segA dies: 4*N1 f32 each
    float* y1  = y0 + 4 * N1;
    float* y2  = y1 + 4 * N1;
    float* y3  = y2 + 4 * N1;
    float* x1b = (float*)base + 16 * N1;                  // [66.4MB, 132.8MB)
    float* x2 = (float*)base;                             // after y dead: 32*N2 f32
    float* z0 = x2 + 32 * N2;
    float* z1 = z0 + 8 * N2;
    float* z2 = z1 + 8 * N2;
    float* z3 = z2 + 8 * N2;                              // ends at 33.2MB < x1b start

    float* out = (float*)d_out;   // reference output dtype is float32

    // 1. zero raw volume + winner (contiguous)
    kz_zero16<<<ZCHUNKS / 256, 256, 0, stream>>>((uint4*)base, ZCHUNKS);

    // 2. deterministic last-write-wins scatter
    kz_scatter_win  <<<NPIX / 256, 256, 0, stream>>>(depth, winner);
    kz_scatter_write<<<NPIX / 256, 256, 0, stream>>>(depth, winner, feat, segA);

    // 3. avg-pool hole-fill, separable, per channel, in-place
    for (int c = 0; c < C0; ++c) {
        bf16* ch = segA + (size_t)c * V;
        kz_sumw<<<V / 256, 256, 0, stream>>>(ch, tmp);
        kz_fill<<<V / 256, 256, 0, stream>>>(ch, tmp);
    }

    // 4. downsample 1 -> x1 f32 [16][N1]
    kz_ds1<<<N1 / 256, 256, 0, stream>>>(segA, w_ds1, x1);

    // 5. bottleneck 1 (ch16, mid4, spatial 120x72x120)
    kz_pw<16, 4, false><<<N1 / 256, 256, 0, stream>>>(x1, b1_win, nullptr, y0, N1);
    kz_bconv<4, 1, 3, 3, 0><<<N1 / 256, 256, 0, stream>>>(y0, b1w133, b1b133, nullptr, nullptr, y1, D1, H1, W1, N1);
    kz_bconv<4, 3, 3, 1, 1><<<N1 / 256, 256, 0, stream>>>(y1, b1w331, b1b331, y1, nullptr, y2, D1, H1, W1, N1);
    kz_bconv<4, 3, 1, 3, 2><<<N1 / 256, 256, 0, stream>>>(y2, b1w313, b1b313, y2, y1, y3, D1, H1, W1, N1);
    kz_pw<4, 16, true><<<N1 / 256, 256, 0, stream>>>(y3, b1wout, x1, x1b, N1);

    // 6. downsample 2 -> x2 f32 [32][N2]
    kz_ds2<<<(N2 + 255) / 256, 256, 0, stream>>>(x1b, w_ds2, x2);

    // 7. bottleneck 2 (ch32, mid8, spatial 60x36x60) -> f32 d_out
    kz_pw<32, 8, false><<<(N2 + 255) / 256, 256, 0, stream>>>(x2, b2_win, nullptr, z0, N2);
    kz_bconv<8, 1, 3, 3, 0><<<(N2 + 255) / 256, 256, 0, stream>>>(z0, b2w133, b2b133, nullptr, nullptr, z1, D2, H2, W2, N2);
    kz_bconv<8, 3, 3, 1, 1><<<(N2 + 255) / 256, 256, 0, stream>>>(z1, b2w331, b2b331, z1, nullptr, z2, D2, H2, W2, N2);
    kz_bconv<8, 3, 1, 3, 2><<<(N2 + 255) / 256, 256, 0, stream>>>(z2, b2w313, b2b313, z2, z1, z3, D2, H2, W2, N2);
    kz_pw<8, 32, true><<<(N2 + 255) / 256, 256, 0, stream>>>(z3, b2wout, x2, out, N2);

    (void)in_sizes; (void)n_in; (void)out_size; (void)ws_size;
}

// Round 6
// 1992.884 us; speedup vs baseline: 2.2922x; 2.2922x over previous
//
#include <hip/hip_runtime.h>
#include <hip/hip_bf16.h>

typedef __hip_bfloat16 bf16;

static __device__ __forceinline__ float b2f(bf16 x) { return __bfloat162float(x); }
static __device__ __forceinline__ bf16  f2b(float x) { return __float2bfloat16(x); }

// ---- problem constants ----
constexpr int D0 = 240, H0 = 144, W0 = 240;
constexpr int V  = D0 * H0 * W0;          // 8,294,400 voxels
constexpr int NPIX = 480 * 640;           // 307,200 pixels
constexpr int C0 = 12;                    // input feature channels
constexpr int D1 = 120, H1 = 72, W1 = 120;
constexpr int N1 = D1 * H1 * W1;          // 1,036,800
constexpr int D2 = 60, H2 = 36, W2 = 60;
constexpr int N2 = D2 * H2 * W2;          // 129,600

constexpr size_t SEG_BYTES = (size_t)C0 * V * sizeof(bf16);   // 199,065,600
constexpr size_t WIN_BYTES = (size_t)V * sizeof(unsigned);    // 33,177,600
constexpr int ZCHUNKS = (int)((SEG_BYTES + WIN_BYTES) / 16);  // 14,515,200 uint4
// Workspace peak: SEG_BYTES + 16*N1*4 = 265,420,800 bytes — proven safe.

// ============================================================
// Zero-fill (uint4)
// ============================================================
__global__ void __launch_bounds__(256) kz_zero16(uint4* __restrict__ p, int nchunks) {
    int i = blockIdx.x * 256 + threadIdx.x;
    if (i >= nchunks) return;
    p[i] = make_uint4(0u, 0u, 0u, 0u);
}

// ============================================================
// Scatter: last-write-wins via winner = max(pixel_index+1)
// ============================================================
__global__ void __launch_bounds__(256) kz_scatter_win(const int* __restrict__ depth,
                                                      unsigned* __restrict__ winner) {
    int p = blockIdx.x * 256 + threadIdx.x;
    if (p >= NPIX) return;
    int d = depth[p];
    if (d > 0 && d < V) atomicMax(&winner[d], (unsigned)(p + 1));
}

__global__ void __launch_bounds__(256) kz_scatter_write(const int* __restrict__ depth,
                                                        const unsigned* __restrict__ winner,
                                                        const float* __restrict__ feat,
                                                        bf16* __restrict__ segA) {
    int p = blockIdx.x * 256 + threadIdx.x;
    if (p >= NPIX) return;
    int d = depth[p];
    if (d > 0 && d < V && winner[d] == (unsigned)(p + 1)) {
#pragma unroll
        for (int c = 0; c < C0; ++c)
            segA[(size_t)c * V + d] = f2b(feat[c * NPIX + p]);
    }
}

// ============================================================
// Fill pass A (one channel): 3-tap sums along W (zero padded) -> f32 tmp
// ============================================================
__global__ void __launch_bounds__(256) kz_sumw(const bf16* __restrict__ seg,
                                               float* __restrict__ tmp) {
    int i = blockIdx.x * 256 + threadIdx.x;
    if (i >= V) return;
    int w = i % W0;
    float s = b2f(seg[i]);
    if (w > 0)      s += b2f(seg[i - 1]);
    if (w < W0 - 1) s += b2f(seg[i + 1]);
    tmp[i] = s;
}

// ============================================================
// Fill pass B (one channel, IN-PLACE): 9-tap (d,h) sum of row-sums, /27, select
// ============================================================
__global__ void __launch_bounds__(256) kz_fill(bf16* __restrict__ raw,
                                               const float* __restrict__ tmp) {
    int i = blockIdx.x * 256 + threadIdx.x;
    if (i >= V) return;
    bf16 rv = raw[i];
    if (b2f(rv) != 0.f) return;               // keep raw value
    int w = i % W0;
    int t = i / W0;
    int h = t % H0;
    int d = t / H0;
    float s = 0.f;
#pragma unroll
    for (int dd = -1; dd <= 1; ++dd) {
        int d2 = d + dd;
        if (d2 < 0 || d2 >= D0) continue;
#pragma unroll
        for (int dh = -1; dh <= 1; ++dh) {
            int h2 = h + dh;
            if (h2 < 0 || h2 >= H0) continue;
            s += tmp[(d2 * H0 + h2) * W0 + w];
        }
    }
    raw[i] = f2b(s * (1.0f / 27.0f));
}

// ============================================================
// Downsample 1: conv3d 12->4 (k3,s2,p1, no bias) ++ maxpool2 of 12ch, relu
// input bf16 [12][V], f32 weights, output f32 [16][N1]
// ============================================================
__global__ void __launch_bounds__(256) kz_ds1(const bf16* __restrict__ seg,
                                              const float* __restrict__ w,
                                              float* __restrict__ out) {
    __shared__ float wl[4 * 12 * 27];
    for (int t = threadIdx.x; t < 4 * 12 * 27; t += 256) wl[t] = w[t];
    __syncthreads();
    int o = blockIdx.x * 256 + threadIdx.x;
    if (o >= N1) return;
    int wo = o % W1;
    int t  = o / W1;
    int ho = t % H1;
    int d0 = t / H1;
    float acc[4] = {0.f, 0.f, 0.f, 0.f};
    for (int ci = 0; ci < 12; ++ci) {
        const bf16* base = seg + (size_t)ci * V;
        const float* wci = wl + ci * 27;
        float mx = -1e30f;
        for (int kd = 0; kd < 3; ++kd) {
            int d2 = 2 * d0 - 1 + kd;
            bool dv = (d2 >= 0 && d2 < D0);
            for (int kh = 0; kh < 3; ++kh) {
                int h2 = 2 * ho - 1 + kh;
                bool hv = (h2 >= 0 && h2 < H0);
                for (int kw = 0; kw < 3; ++kw) {
                    int w2 = 2 * wo - 1 + kw;
                    float v = 0.f;
                    if (dv && hv && w2 >= 0 && w2 < W0)
                        v = b2f(base[(d2 * H0 + h2) * W0 + w2]);
                    int wi = kd * 9 + kh * 3 + kw;
#pragma unroll
                    for (int m = 0; m < 4; ++m) acc[m] += v * wci[m * 324 + wi];
                    if (kd >= 1 && kh >= 1 && kw >= 1) mx = fmaxf(mx, v);  // pool = inner 2x2x2
                }
            }
        }
        out[(4 + ci) * N1 + o] = fmaxf(mx, 0.f);
    }
#pragma unroll
    for (int m = 0; m < 4; ++m) out[m * N1 + o] = fmaxf(acc[m], 0.f);
}

// ============================================================
// Downsample 2: conv3d 16->16 (k3,s2,p1) ++ maxpool2 of 16ch, relu (f32 in/out)
// ============================================================
__global__ void __launch_bounds__(256) kz_ds2(const float* __restrict__ in,
                                              const float* __restrict__ w,
                                              float* __restrict__ out) {
    __shared__ float wl[16 * 16 * 27];
    for (int t = threadIdx.x; t < 16 * 16 * 27; t += 256) wl[t] = w[t];
    __syncthreads();
    int o = blockIdx.x * 256 + threadIdx.x;
    if (o >= N2) return;
    int wo = o % W2;
    int t  = o / W2;
    int ho = t % H2;
    int d0 = t / H2;
    float acc[16];
#pragma unroll
    for (int m = 0; m < 16; ++m) acc[m] = 0.f;
    for (int ci = 0; ci < 16; ++ci) {
        const float* base = in + ci * N1;
        const float* wci = wl + ci * 27;
        float mx = -1e30f;
        for (int kd = 0; kd < 3; ++kd) {
            int d2 = 2 * d0 - 1 + kd;
            bool dv = (d2 >= 0 && d2 < D1);
            for (int kh = 0; kh < 3; ++kh) {
                int h2 = 2 * ho - 1 + kh;
                bool hv = (h2 >= 0 && h2 < H1);
                for (int kw = 0; kw < 3; ++kw) {
                    int w2 = 2 * wo - 1 + kw;
                    float v = 0.f;
                    if (dv && hv && w2 >= 0 && w2 < W1)
                        v = base[(d2 * H1 + h2) * W1 + w2];
                    int wi = kd * 9 + kh * 3 + kw;
#pragma unroll
                    for (int m = 0; m < 16; ++m) acc[m] += v * wci[m * 432 + wi];
                    if (kd >= 1 && kh >= 1 && kw >= 1) mx = fmaxf(mx, v);
                }
            }
        }
        out[(16 + ci) * N2 + o] = fmaxf(mx, 0.f);
    }
#pragma unroll
    for (int m = 0; m < 16; ++m) out[m * N2 + o] = fmaxf(acc[m], 0.f);
}

// ============================================================
// Pointwise (1x1x1) conv, optional residual, relu, f32 out
// ============================================================
template <int CIN, int COUT, bool HASRES>
__global__ void __launch_bounds__(256) kz_pw(const float* __restrict__ in,
                                             const float* __restrict__ w,
                                             const float* __restrict__ res,
                                             float* __restrict__ outf, int N) {
    __shared__ float wl[CIN * COUT];
    for (int t = threadIdx.x; t < CIN * COUT; t += 256) wl[t] = w[t];
    __syncthreads();
    int o = blockIdx.x * 256 + threadIdx.x;
    if (o >= N) return;
    float acc[COUT];
#pragma unroll
    for (int m = 0; m < COUT; ++m) acc[m] = 0.f;
    for (int ci = 0; ci < CIN; ++ci) {
        float v = in[ci * N + o];
#pragma unroll
        for (int m = 0; m < COUT; ++m) acc[m] += v * wl[m * CIN + ci];
    }
#pragma unroll
    for (int m = 0; m < COUT; ++m) {
        float r = acc[m];
        if (HASRES) r += res[m * N + o];
        outf[m * N + o] = fmaxf(r, 0.f);
    }
}

// ============================================================
// Bottleneck middle conv: C->C, kernel (KD,KH,KW) same-pad on >1 dims,
// + bias + up to 2 residual adds + relu. f32 in/out.
// ============================================================
template <int C, int KD, int KH, int KW, int NADD>
__global__ void __launch_bounds__(256) kz_bconv(const float* __restrict__ in,
                                                const float* __restrict__ w,
                                                const float* __restrict__ b,
                                                const float* __restrict__ add1,
                                                const float* __restrict__ add2,
                                                float* __restrict__ out,
                                                int Dd, int Hh, int Ww, int N) {
    __shared__ float wl[C * C * KD * KH * KW];
    __shared__ float bl[C];
    for (int t = threadIdx.x; t < C * C * KD * KH * KW; t += 256) wl[t] = w[t];
    if (threadIdx.x < C) bl[threadIdx.x] = b[threadIdx.x];
    __syncthreads();
    int o = blockIdx.x * 256 + threadIdx.x;
    if (o >= N) return;
    int wo = o % Ww;
    int t  = o / Ww;
    int ho = t % Hh;
    int d0 = t / Hh;
    float acc[C];
#pragma unroll
    for (int m = 0; m < C; ++m) acc[m] = bl[m];
    for (int ci = 0; ci < C; ++ci) {
        const float* base = in + ci * N;
        const float* wci = wl + ci * KD * KH * KW;
#pragma unroll
        for (int kd = 0; kd < KD; ++kd) {
            int d2 = d0 + kd - KD / 2;
            if (d2 < 0 || d2 >= Dd) continue;
#pragma unroll
            for (int kh = 0; kh < KH; ++kh) {
                int h2 = ho + kh - KH / 2;
                if (h2 < 0 || h2 >= Hh) continue;
#pragma unroll
                for (int kw = 0; kw < KW; ++kw) {
                    int w2 = wo + kw - KW / 2;
                    if (w2 < 0 || w2 >= Ww) continue;
                    float v = base[(d2 * Hh + h2) * Ww + w2];
                    int wi = kd * KH * KW + kh * KW + kw;
#pragma unroll
                    for (int m = 0; m < C; ++m)
                        acc[m] += v * wci[m * C * KD * KH * KW + wi];
                }
            }
        }
    }
#pragma unroll
    for (int m = 0; m < C; ++m) {
        float r = acc[m];
        if (NADD >= 1) r += add1[m * N + o];
        if (NADD >= 2) r += add2[m * N + o];
        out[m * N + o] = fmaxf(r, 0.f);
    }
}

// ============================================================
extern "C" void kernel_launch(void* const* d_in, const int* in_sizes, int n_in,
                              void* d_out, int out_size, void* d_ws, size_t ws_size,
                              hipStream_t stream) {
    const float* feat   = (const float*)d_in[0];
    const int*   depth  = (const int*)d_in[1];
    const float* w_ds1  = (const float*)d_in[2];
    const float* b1_win = (const float*)d_in[3];
    const float* b1w133 = (const float*)d_in[4];
    const float* b1b133 = (const float*)d_in[5];
    const float* b1w331 = (const float*)d_in[6];
    const float* b1b331 = (const float*)d_in[7];
    const float* b1w313 = (const float*)d_in[8];
    const float* b1b313 = (const float*)d_in[9];
    const float* b1wout = (const float*)d_in[10];
    const float* w_ds2  = (const float*)d_in[11];
    const float* b2_win = (const float*)d_in[12];
    const float* b2w133 = (const float*)d_in[13];
    const float* b2b133 = (const float*)d_in[14];
    const float* b2w331 = (const float*)d_in[15];
    const float* b2b331 = (const float*)d_in[16];
    const float* b2w313 = (const float*)d_in[17];
    const float* b2b313 = (const float*)d_in[18];
    const float* b2wout = (const float*)d_in[19];

    char* base = (char*)d_ws;

    // --- Region layout (time-shared; peak = SEG_BYTES + 66.4MB = 265.4 MB) ---
    bf16* segA = (bf16*)base;                             // [0, SEG) raw volume, filled in-place
    unsigned* winner = (unsigned*)(base + SEG_BYTES);     // [SEG, SEG+33.2MB)
    float*    tmp    = (float*)(base + SEG_BYTES);        // same region (f32[V]), after winner dies
    float*    x1     = (float*)(base + SEG_BYTES);        // same region, after tmp dies (16*N1 f32)
    float* y0  = (float*)base;                            // after segA dies: 4*N1 f32 each
    float* y1  = y0 + 4 * N1;
    float* y2  = y1 + 4 * N1;
    float* y3  = y2 + 4 * N1;
    float* x1b = (float*)base + 16 * N1;                  // [66.4MB, 132.8MB)
    float* x2 = (float*)base;                             // after y dead: 32*N2 f32
    float* z0 = x2 + 32 * N2;
    float* z1 = z0 + 8 * N2;
    float* z2 = z1 + 8 * N2;
    float* z3 = z2 + 8 * N2;                              // ends at 33.2MB < x1b start

    float* out = (float*)d_out;   // reference output dtype is float32

    // 1. zero raw volume + winner (contiguous)
    kz_zero16<<<ZCHUNKS / 256, 256, 0, stream>>>((uint4*)base, ZCHUNKS);

    // 2. deterministic last-write-wins scatter
    kz_scatter_win  <<<NPIX / 256, 256, 0, stream>>>(depth, winner);
    kz_scatter_write<<<NPIX / 256, 256, 0, stream>>>(depth, winner, feat, segA);

    // 3. avg-pool hole-fill, separable, per channel, in-place
    for (int c = 0; c < C0; ++c) {
        bf16* ch = segA + (size_t)c * V;
        kz_sumw<<<V / 256, 256, 0, stream>>>(ch, tmp);
        kz_fill<<<V / 256, 256, 0, stream>>>(ch, tmp);
    }

    // 4. downsample 1 -> x1 f32 [16][N1]
    kz_ds1<<<N1 / 256, 256, 0, stream>>>(segA, w_ds1, x1);

    // 5. bottleneck 1 (ch16, mid4, spatial 120x72x120)
    kz_pw<16, 4, false><<<N1 / 256, 256, 0, stream>>>(x1, b1_win, nullptr, y0, N1);
    kz_bconv<4, 1, 3, 3, 0><<<N1 / 256, 256, 0, stream>>>(y0, b1w133, b1b133, nullptr, nullptr, y1, D1, H1, W1, N1);
    kz_bconv<4, 3, 3, 1, 1><<<N1 / 256, 256, 0, stream>>>(y1, b1w331, b1b331, y1, nullptr, y2, D1, H1, W1, N1);
    kz_bconv<4, 3, 1, 3, 2><<<N1 / 256, 256, 0, stream>>>(y2, b1w313, b1b313, y2, y1, y3, D1, H1, W1, N1);
    kz_pw<4, 16, true><<<N1 / 256, 256, 0, stream>>>(y3, b1wout, x1, x1b, N1);

    // 6. downsample 2 -> x2 f32 [32][N2]
    kz_ds2<<<(N2 + 255) / 256, 256, 0, stream>>>(x1b, w_ds2, x2);

    // 7. bottleneck 2 (ch32, mid8, spatial 60x36x60) -> f32 d_out
    kz_pw<32, 8, false><<<(N2 + 255) / 256, 256, 0, stream>>>(x2, b2_win, nullptr, z0, N2);
    kz_bconv<8, 1, 3, 3, 0><<<(N2 + 255) / 256, 256, 0, stream>>>(z0, b2w133, b2b133, nullptr, nullptr, z1, D2, H2, W2, N2);
    kz_bconv<8, 3, 3, 1, 1><<<(N2 + 255) / 256, 256, 0, stream>>>(z1, b2w331, b2b331, z1, nullptr, z2, D2, H2, W2, N2);
    kz_bconv<8, 3, 1, 3, 2><<<(N2 + 255) / 256, 256, 0, stream>>>(z2, b2w313, b2b313, z2, z1, z3, D2, H2, W2, N2);
    kz_pw<8, 32, true><<<(N2 + 255) / 256, 256, 0, stream>>>(z3, b2wout, x2, out, N2);

    (void)in_sizes; (void)n_in; (void)out_size; (void)ws_size;
}

// Round 7
// 1337.445 us; speedup vs baseline: 3.4156x; 1.4901x over previous
//
#include <hip/hip_runtime.h>
#include <hip/hip_bf16.h>

typedef __hip_bfloat16 bf16;
typedef unsigned short u16;

static __device__ __forceinline__ float b2f(bf16 x) { return __bfloat162float(x); }
static __device__ __forceinline__ bf16  f2b(float x) { return __float2bfloat16(x); }
// bf16 bits (u16) -> f32, exact
static __device__ __forceinline__ float u2f(u16 u) { return __uint_as_float(((unsigned)u) << 16); }
// f32 -> bf16 bits, round-to-nearest-even (no NaN inputs in this pipeline)
static __device__ __forceinline__ u16 f2u(float x) {
    unsigned u = __float_as_uint(x);
    return (u16)((u + 0x7FFFu + ((u >> 16) & 1u)) >> 16);
}

// ---- problem constants ----
constexpr int D0 = 240, H0 = 144, W0 = 240;
constexpr int V  = D0 * H0 * W0;          // 8,294,400 voxels
constexpr int NPIX = 480 * 640;           // 307,200 pixels
constexpr int C0 = 12;                    // input feature channels
constexpr int D1 = 120, H1 = 72, W1 = 120;
constexpr int N1 = D1 * H1 * W1;          // 1,036,800
constexpr int D2 = 60, H2 = 36, W2 = 60;
constexpr int N2 = D2 * H2 * W2;          // 129,600
constexpr int VHALF = V / 2;              // 4,147,200 pairs per channel

constexpr size_t SEG_BYTES = (size_t)C0 * V * sizeof(bf16);   // 199,065,600
constexpr size_t WIN_BYTES = (size_t)V * sizeof(unsigned);    // 33,177,600
constexpr int ZCHUNKS = (int)((SEG_BYTES + WIN_BYTES) / 16);  // 14,515,200 uint4
// Workspace peak: SEG_BYTES + 16*N1*4 = 265,420,800 bytes — proven safe.

// ============================================================
// Zero-fill (uint4)
// ============================================================
__global__ void __launch_bounds__(256) kz_zero16(uint4* __restrict__ p, int nchunks) {
    int i = blockIdx.x * 256 + threadIdx.x;
    if (i >= nchunks) return;
    p[i] = make_uint4(0u, 0u, 0u, 0u);
}

// ============================================================
// Scatter: last-write-wins via winner = max(pixel_index+1)
// ============================================================
__global__ void __launch_bounds__(256) kz_scatter_win(const int* __restrict__ depth,
                                                      unsigned* __restrict__ winner) {
    int p = blockIdx.x * 256 + threadIdx.x;
    if (p >= NPIX) return;
    int d = depth[p];
    if (d > 0 && d < V) atomicMax(&winner[d], (unsigned)(p + 1));
}

__global__ void __launch_bounds__(256) kz_scatter_write(const int* __restrict__ depth,
                                                        const unsigned* __restrict__ winner,
                                                        const float* __restrict__ feat,
                                                        bf16* __restrict__ segA) {
    int p = blockIdx.x * 256 + threadIdx.x;
    if (p >= NPIX) return;
    int d = depth[p];
    if (d > 0 && d < V && winner[d] == (unsigned)(p + 1)) {
#pragma unroll
        for (int c = 0; c < C0; ++c)
            segA[(size_t)c * V + d] = f2b(feat[c * NPIX + p]);
    }
}

// ============================================================
// Fill pass A, 4 channels, 2 voxels/thread: 3-tap W sums -> bf16 tmp
// ============================================================
__global__ void __launch_bounds__(256) kz_sumw4(const u16* __restrict__ seg4,  // 4-ch base
                                                u16* __restrict__ tmp4) {      // 4-ch tmp
    int pid = blockIdx.x * 256 + threadIdx.x;    // grid exact: 4*VHALF/256
    int c   = pid / VHALF;
    int r   = pid - c * VHALF;
    int i   = 2 * r;                              // even index within channel
    const u16* sb = seg4 + (size_t)c * V;
    u16* tb = tmp4 + (size_t)c * V;
    int w = i % W0;                               // even
    ushort2 cu = *(const ushort2*)(sb + i);
    float x0 = u2f(cu.x), x1 = u2f(cu.y);
    float pl = 0.f, nl = 0.f;
    if (w > 0)   { ushort2 p = *(const ushort2*)(sb + i - 2); pl = u2f(p.y); }
    if (w < 238) { ushort2 n = *(const ushort2*)(sb + i + 2); nl = u2f(n.x); }
    ushort2 o2;
    o2.x = f2u(pl + x0 + x1);
    o2.y = f2u(x0 + x1 + nl);
    *(ushort2*)(tb + i) = o2;
}

// ============================================================
// Fill pass B, 4 channels, 2 voxels/thread, IN-PLACE:
// 9-tap (d,h) sum of W row-sums, /27, only where raw==0
// ============================================================
__global__ void __launch_bounds__(256) kz_fill4(u16* __restrict__ raw4,
                                                const u16* __restrict__ tmp4) {
    int pid = blockIdx.x * 256 + threadIdx.x;
    int c   = pid / VHALF;
    int r   = pid - c * VHALF;
    int i   = 2 * r;
    u16* rb = raw4 + (size_t)c * V;
    const u16* tb = tmp4 + (size_t)c * V;
    ushort2 rv = *(const ushort2*)(rb + i);
    bool z0 = (rv.x & 0x7FFFu) == 0;   // bf16 ±0
    bool z1 = (rv.y & 0x7FFFu) == 0;
    if (!z0 && !z1) return;
    int w = i % W0;
    int t = i / W0;
    int h = t % H0;
    int d = t / H0;
    float s0 = 0.f, s1 = 0.f;
#pragma unroll
    for (int dd = -1; dd <= 1; ++dd) {
        int d2 = d + dd;
        if (d2 < 0 || d2 >= D0) continue;
#pragma unroll
        for (int dh = -1; dh <= 1; ++dh) {
            int h2 = h + dh;
            if (h2 < 0 || h2 >= H0) continue;
            ushort2 tp = *(const ushort2*)(tb + (d2 * H0 + h2) * W0 + w);
            s0 += u2f(tp.x);
            s1 += u2f(tp.y);
        }
    }
    if (z0 && z1) {
        ushort2 o2; o2.x = f2u(s0 * (1.0f / 27.0f)); o2.y = f2u(s1 * (1.0f / 27.0f));
        *(ushort2*)(rb + i) = o2;
    } else if (z0) {
        rb[i] = f2u(s0 * (1.0f / 27.0f));
    } else {
        rb[i + 1] = f2u(s1 * (1.0f / 27.0f));
    }
}

// ============================================================
// Downsample 1: conv3d 12->4 (k3,s2,p1) ++ maxpool2 of 12ch, relu
// bf16 volume in, f32 weights, f32 out [16][N1]. Paired W loads.
// ============================================================
__global__ void __launch_bounds__(256) kz_ds1(const u16* __restrict__ seg,
                                              const float* __restrict__ w,
                                              float* __restrict__ out) {
    __shared__ float wl[4 * 12 * 27];
    for (int t = threadIdx.x; t < 4 * 12 * 27; t += 256) wl[t] = w[t];
    __syncthreads();
    int o = blockIdx.x * 256 + threadIdx.x;
    if (o >= N1) return;
    int wo = o % W1;
    int t  = o / W1;
    int ho = t % H1;
    int d0 = t / H1;
    float acc[4] = {0.f, 0.f, 0.f, 0.f};
    for (int ci = 0; ci < 12; ++ci) {
        const u16* base = seg + (size_t)ci * V;
        const float* wci = wl + ci * 27;
        float mx = -1e30f;
#pragma unroll
        for (int kd = 0; kd < 3; ++kd) {
            int d2 = 2 * d0 - 1 + kd;
            bool dv = (d2 >= 0 && d2 < D0);
#pragma unroll
            for (int kh = 0; kh < 3; ++kh) {
                int h2 = 2 * ho - 1 + kh;
                bool rvv = dv && (h2 >= 0 && h2 < H0);
                float vm1 = 0.f, v0 = 0.f, v1 = 0.f;
                if (rvv) {
                    int r2 = (d2 * H0 + h2) * W0 + 2 * wo;
                    ushort2 pb = *(const ushort2*)(base + r2);      // w2 = 2wo, 2wo+1
                    v0 = u2f(pb.x); v1 = u2f(pb.y);
                    if (wo > 0) {
                        ushort2 pa = *(const ushort2*)(base + r2 - 2);
                        vm1 = u2f(pa.y);                            // w2 = 2wo-1
                    }
                }
                const float* wk = wci + kd * 9 + kh * 3;
#pragma unroll
                for (int m = 0; m < 4; ++m)
                    acc[m] += vm1 * wk[m * 324] + v0 * wk[m * 324 + 1] + v1 * wk[m * 324 + 2];
                if (kd >= 1 && kh >= 1) mx = fmaxf(mx, fmaxf(v0, v1));  // pool = inner 2x2x2
            }
        }
        out[(4 + ci) * N1 + o] = fmaxf(mx, 0.f);
    }
#pragma unroll
    for (int m = 0; m < 4; ++m) out[m * N1 + o] = fmaxf(acc[m], 0.f);
}

// ============================================================
// Downsample 2: conv3d 16->16 (k3,s2,p1) ++ maxpool2 of 16ch, relu
// f32 in/out. Paired W loads (float2).
// ============================================================
__global__ void __launch_bounds__(256) kz_ds2(const float* __restrict__ in,
                                              const float* __restrict__ w,
                                              float* __restrict__ out) {
    __shared__ float wl[16 * 16 * 27];
    for (int t = threadIdx.x; t < 16 * 16 * 27; t += 256) wl[t] = w[t];
    __syncthreads();
    int o = blockIdx.x * 256 + threadIdx.x;
    if (o >= N2) return;
    int wo = o % W2;
    int t  = o / W2;
    int ho = t % H2;
    int d0 = t / H2;
    float acc[16];
#pragma unroll
    for (int m = 0; m < 16; ++m) acc[m] = 0.f;
    for (int ci = 0; ci < 16; ++ci) {
        const float* base = in + ci * N1;
        const float* wci = wl + ci * 27;
        float mx = -1e30f;
#pragma unroll
        for (int kd = 0; kd < 3; ++kd) {
            int d2 = 2 * d0 - 1 + kd;
            bool dv = (d2 >= 0 && d2 < D1);
#pragma unroll
            for (int kh = 0; kh < 3; ++kh) {
                int h2 = 2 * ho - 1 + kh;
                bool rvv = dv && (h2 >= 0 && h2 < H1);
                float vm1 = 0.f, v0 = 0.f, v1 = 0.f;
                if (rvv) {
                    int r2 = (d2 * H1 + h2) * W1 + 2 * wo;
                    float2 pb = *(const float2*)(base + r2);
                    v0 = pb.x; v1 = pb.y;
                    if (wo > 0) {
                        float2 pa = *(const float2*)(base + r2 - 2);
                        vm1 = pa.y;
                    }
                }
                const float* wk = wci + kd * 9 + kh * 3;
#pragma unroll
                for (int m = 0; m < 16; ++m)
                    acc[m] += vm1 * wk[m * 432] + v0 * wk[m * 432 + 1] + v1 * wk[m * 432 + 2];
                if (kd >= 1 && kh >= 1) mx = fmaxf(mx, fmaxf(v0, v1));
            }
        }
        out[(16 + ci) * N2 + o] = fmaxf(mx, 0.f);
    }
#pragma unroll
    for (int m = 0; m < 16; ++m) out[m * N2 + o] = fmaxf(acc[m], 0.f);
}

// ============================================================
// Pointwise (1x1x1) conv, optional residual, relu, f32 out
// ============================================================
template <int CIN, int COUT, bool HASRES>
__global__ void __launch_bounds__(256) kz_pw(const float* __restrict__ in,
                                             const float* __restrict__ w,
                                             const float* __restrict__ res,
                                             float* __restrict__ outf, int N) {
    __shared__ float wl[CIN * COUT];
    for (int t = threadIdx.x; t < CIN * COUT; t += 256) wl[t] = w[t];
    __syncthreads();
    int o = blockIdx.x * 256 + threadIdx.x;
    if (o >= N) return;
    float acc[COUT];
#pragma unroll
    for (int m = 0; m < COUT; ++m) acc[m] = 0.f;
    for (int ci = 0; ci < CIN; ++ci) {
        float v = in[ci * N + o];
#pragma unroll
        for (int m = 0; m < COUT; ++m) acc[m] += v * wl[m * CIN + ci];
    }
#pragma unroll
    for (int m = 0; m < COUT; ++m) {
        float r = acc[m];
        if (HASRES) r += res[m * N + o];
        outf[m * N + o] = fmaxf(r, 0.f);
    }
}

// ============================================================
// Bottleneck middle conv: C->C, kernel (KD,KH,KW) same-pad on >1 dims,
// + bias + up to 2 residual adds + relu. f32 in/out.
// ============================================================
template <int C, int KD, int KH, int KW, int NADD>
__global__ void __launch_bounds__(256) kz_bconv(const float* __restrict__ in,
                                                const float* __restrict__ w,
                                                const float* __restrict__ b,
                                                const float* __restrict__ add1,
                                                const float* __restrict__ add2,
                                                float* __restrict__ out,
                                                int Dd, int Hh, int Ww, int N) {
    __shared__ float wl[C * C * KD * KH * KW];
    __shared__ float bl[C];
    for (int t = threadIdx.x; t < C * C * KD * KH * KW; t += 256) wl[t] = w[t];
    if (threadIdx.x < C) bl[threadIdx.x] = b[threadIdx.x];
    __syncthreads();
    int o = blockIdx.x * 256 + threadIdx.x;
    if (o >= N) return;
    int wo = o % Ww;
    int t  = o / Ww;
    int ho = t % Hh;
    int d0 = t / Hh;
    float acc[C];
#pragma unroll
    for (int m = 0; m < C; ++m) acc[m] = bl[m];
    for (int ci = 0; ci < C; ++ci) {
        const float* base = in + ci * N;
        const float* wci = wl + ci * KD * KH * KW;
#pragma unroll
        for (int kd = 0; kd < KD; ++kd) {
            int d2 = d0 + kd - KD / 2;
            if (d2 < 0 || d2 >= Dd) continue;
#pragma unroll
            for (int kh = 0; kh < KH; ++kh) {
                int h2 = ho + kh - KH / 2;
                if (h2 < 0 || h2 >= Hh) continue;
#pragma unroll
                for (int kw = 0; kw < KW; ++kw) {
                    int w2 = wo + kw - KW / 2;
                    if (w2 < 0 || w2 >= Ww) continue;
                    float v = base[(d2 * Hh + h2) * Ww + w2];
                    int wi = kd * KH * KW + kh * KW + kw;
#pragma unroll
                    for (int m = 0; m < C; ++m)
                        acc[m] += v * wci[m * C * KD * KH * KW + wi];
                }
            }
        }
    }
#pragma unroll
    for (int m = 0; m < C; ++m) {
        float r = acc[m];
        if (NADD >= 1) r += add1[m * N + o];
        if (NADD >= 2) r += add2[m * N + o];
        out[m * N + o] = fmaxf(r, 0.f);
    }
}

// ============================================================
extern "C" void kernel_launch(void* const* d_in, const int* in_sizes, int n_in,
                              void* d_out, int out_size, void* d_ws, size_t ws_size,
                              hipStream_t stream) {
    const float* feat   = (const float*)d_in[0];
    const int*   depth  = (const int*)d_in[1];
    const float* w_ds1  = (const float*)d_in[2];
    const float* b1_win = (const float*)d_in[3];
    const float* b1w133 = (const float*)d_in[4];
    const float* b1b133 = (const float*)d_in[5];
    const float* b1w331 = (const float*)d_in[6];
    const float* b1b331 = (const float*)d_in[7];
    const float* b1w313 = (const float*)d_in[8];
    const float* b1b313 = (const float*)d_in[9];
    const float* b1wout = (const float*)d_in[10];
    const float* w_ds2  = (const float*)d_in[11];
    const float* b2_win = (const float*)d_in[12];
    const float* b2w133 = (const float*)d_in[13];
    const float* b2b133 = (const float*)d_in[14];
    const float* b2w331 = (const float*)d_in[15];
    const float* b2b331 = (const float*)d_in[16];
    const float* b2w313 = (const float*)d_in[17];
    const float* b2b313 = (const float*)d_in[18];
    const float* b2wout = (const float*)d_in[19];

    char* base = (char*)d_ws;

    // --- Region layout (time-shared; peak = SEG_BYTES + 66.4MB = 265.4 MB) ---
    bf16* segA = (bf16*)base;                             // [0, SEG) raw volume, filled in-place
    u16*  segAu = (u16*)base;
    unsigned* winner = (unsigned*)(base + SEG_BYTES);     // [SEG, SEG+33.2MB)
    u16*      tmpu   = (u16*)(base + SEG_BYTES);          // bf16[4*V] = 66.4MB, after winner dies
    float*    x1     = (float*)(base + SEG_BYTES);        // 16*N1 f32 = 66.4MB, after tmp dies
    float* y0  = (float*)base;                            // after segA dies: 4*N1 f32 each
    float* y1  = y0 + 4 * N1;
    float* y2  = y1 + 4 * N1;
    float* y3  = y2 + 4 * N1;
    float* x1b = (float*)base + 16 * N1;                  // [66.4MB, 132.8MB)
    float* x2 = (float*)base;                             // after y dead: 32*N2 f32
    float* z0 = x2 + 32 * N2;
    float* z1 = z0 + 8 * N2;
    float* z2 = z1 + 8 * N2;
    float* z3 = z2 + 8 * N2;                              // ends at 33.2MB < x1b start

    float* out = (float*)d_out;   // reference output dtype is float32

    // 1. zero raw volume + winner (contiguous)
    kz_zero16<<<ZCHUNKS / 256, 256, 0, stream>>>((uint4*)base, ZCHUNKS);

    // 2. deterministic last-write-wins scatter
    kz_scatter_win  <<<NPIX / 256, 256, 0, stream>>>(depth, winner);
    kz_scatter_write<<<NPIX / 256, 256, 0, stream>>>(depth, winner, feat, segA);

    // 3. avg-pool hole-fill, separable, 4 channels per launch, in-place
    for (int cg = 0; cg < 3; ++cg) {
        u16* ch4 = segAu + (size_t)cg * 4 * V;
        kz_sumw4<<<(4 * VHALF) / 256, 256, 0, stream>>>(ch4, tmpu);
        kz_fill4<<<(4 * VHALF) / 256, 256, 0, stream>>>(ch4, tmpu);
    }

    // 4. downsample 1 -> x1 f32 [16][N1]
    kz_ds1<<<N1 / 256, 256, 0, stream>>>(segAu, w_ds1, x1);

    // 5. bottleneck 1 (ch16, mid4, spatial 120x72x120)
    kz_pw<16, 4, false><<<N1 / 256, 256, 0, stream>>>(x1, b1_win, nullptr, y0, N1);
    kz_bconv<4, 1, 3, 3, 0><<<N1 / 256, 256, 0, stream>>>(y0, b1w133, b1b133, nullptr, nullptr, y1, D1, H1, W1, N1);
    kz_bconv<4, 3, 3, 1, 1><<<N1 / 256, 256, 0, stream>>>(y1, b1w331, b1b331, y1, nullptr, y2, D1, H1, W1, N1);
    kz_bconv<4, 3, 1, 3, 2><<<N1 / 256, 256, 0, stream>>>(y2, b1w313, b1b313, y2, y1, y3, D1, H1, W1, N1);
    kz_pw<4, 16, true><<<N1 / 256, 256, 0, stream>>>(y3, b1wout, x1, x1b, N1);

    // 6. downsample 2 -> x2 f32 [32][N2]
    kz_ds2<<<(N2 + 255) / 256, 256, 0, stream>>>(x1b, w_ds2, x2);

    // 7. bottleneck 2 (ch32, mid8, spatial 60x36x60) -> f32 d_out
    kz_pw<32, 8, false><<<(N2 + 255) / 256, 256, 0, stream>>>(x2, b2_win, nullptr, z0, N2);
    kz_bconv<8, 1, 3, 3, 0><<<(N2 + 255) / 256, 256, 0, stream>>>(z0, b2w133, b2b133, nullptr, nullptr, z1, D2, H2, W2, N2);
    kz_bconv<8, 3, 3, 1, 1><<<(N2 + 255) / 256, 256, 0, stream>>>(z1, b2w331, b2b331, z1, nullptr, z2, D2, H2, W2, N2);
    kz_bconv<8, 3, 1, 3, 2><<<(N2 + 255) / 256, 256, 0, stream>>>(z2, b2w313, b2b313, z2, z1, z3, D2, H2, W2, N2);
    kz_pw<8, 32, true><<<(N2 + 255) / 256, 256, 0, stream>>>(z3, b2wout, x2, out, N2);

    (void)in_sizes; (void)n_in; (void)out_size; (void)ws_size;
}